// Round 3
// baseline (236.105 us; speedup 1.0000x reference)
//
#include <hip/hip_runtime.h>
#include <hip/hip_bf16.h>
#include <stdint.h>

#define BROWS 16384
#define DIM   256
#define BM    256
#define BN    256
#define BK    64
#define NBM   (BROWS / BM)      // 64 row blocks
#define NBN   (BROWS / BN)      // 64 col blocks
#define NCHUNK 256              // 64-wide column chunks per row (64 bn * 4 wc)

typedef __attribute__((ext_vector_type(8))) short bf16x8;
typedef __attribute__((ext_vector_type(4))) float f32x4;

__device__ __forceinline__ float b2f(unsigned short u) {
  return __uint_as_float(((unsigned)u) << 16);
}
__device__ __forceinline__ unsigned short f2b(float f) {
  unsigned u = __float_as_uint(f);
  u += 0x7fffu + ((u >> 16) & 1u);   // RNE
  return (unsigned short)(u >> 16);
}

__device__ __forceinline__ void gload_lds16(const void* g, void* l) {
  __builtin_amdgcn_global_load_lds(
      (const __attribute__((address_space(1))) void*)g,
      (__attribute__((address_space(3))) void*)l, 16, 0, 0);
}

// ---------------- Kernel A: row-normalize f32 -> bf16 ----------------
__global__ void normalize_rows(const float* __restrict__ in,
                               unsigned short* __restrict__ out) {
  int row  = blockIdx.x * 4 + (threadIdx.x >> 6);
  int lane = threadIdx.x & 63;
  float4 v = *(reinterpret_cast<const float4*>(in + (size_t)row * DIM) + lane);
  float ss = v.x * v.x + v.y * v.y + v.z * v.z + v.w * v.w;
#pragma unroll
  for (int m = 1; m < 64; m <<= 1) ss += __shfl_xor(ss, m);
  float r = rsqrtf(ss);
  ushort4 o;
  o.x = f2b(v.x * r);
  o.y = f2b(v.y * r);
  o.z = f2b(v.z * r);
  o.w = f2b(v.w * r);
  *(reinterpret_cast<ushort4*>(out + (size_t)row * DIM) + lane) = o;
}

// Stage one 256x64 K-tile of a matrix into LDS (4 gloads/thread).
// LDS dest linear (wave-uniform base + lane*16); global SOURCE granule carries
// the bank swizzle: LDS granule h of row r holds global granule h^(r&7).
__device__ __forceinline__ void stage_mat(const unsigned short* gmat, int kt,
                                          unsigned short* slot, int wid, int lane) {
#pragma unroll
  for (int p = 0; p < 4; ++p) {
    int row  = p * 64 + wid * 8 + (lane >> 3);
    int goff = kt * BK + (((lane & 7) ^ (row & 7)) << 3);
    gload_lds16(gmat + (size_t)row * DIM + goff,
                (char*)slot + p * 8192 + wid * 1024);
  }
}

// Swizzled fragment read: row r, wanted 16B granule gk (0..7)
__device__ __forceinline__ bf16x8 ldsfrag(const unsigned short* slot, int row, int gk) {
  return *reinterpret_cast<const bf16x8*>(slot + row * 64 + ((gk ^ (row & 7)) << 3));
}

// ---------------- Kernel B: 256x256 8-phase GEMM + exp + partial sums ----------------
// 8 waves (2M x 4N), wave tile 128x64, 16x16x32 bf16 MFMA. K=256 = 4 K-tiles
// of BK=64, fully unrolled. Double-buffered 128 KiB LDS. Counted vmcnt;
// raw s_barrier (no full drains); setprio around MFMA clusters (T5).
__global__ __launch_bounds__(512, 2) void gemm_expsum(
    const unsigned short* __restrict__ A,   // ohat [BROWS][DIM]
    const unsigned short* __restrict__ Bm,  // that [BROWS][DIM] (rows = logits cols)
    float* __restrict__ partial) {
  __shared__ unsigned short smem[2 * 2 * BM * BK];  // 128 KiB
  // slot s: A at s*32768, B at s*32768+16384 (elements)

  const int tid  = threadIdx.x;
  const int lane = tid & 63;
  const int wid  = tid >> 6;
  const int wr   = wid >> 2;    // 0..1  (M half: 128 rows)
  const int wc   = wid & 3;     // 0..3  (N strip: 64 cols)
  const int bm   = blockIdx.x & (NBM - 1);
  const int bn   = blockIdx.x >> 6;

  const unsigned short* gA = A  + (size_t)bm * BM * DIM;
  const unsigned short* gB = Bm + (size_t)bn * BN * DIM;

  f32x4 acc[8][4];
#pragma unroll
  for (int m = 0; m < 8; ++m)
#pragma unroll
    for (int n = 0; n < 4; ++n) acc[m][n] = (f32x4){0.f, 0.f, 0.f, 0.f};

  // ---- prologue: stage T0 -> slot0, T1 -> slot1; wait T0 only ----
  stage_mat(gA, 0, smem,                 wid, lane);
  stage_mat(gB, 0, smem + 16384,         wid, lane);
  stage_mat(gA, 1, smem + 32768,         wid, lane);
  stage_mat(gB, 1, smem + 32768 + 16384, wid, lane);
  asm volatile("s_waitcnt vmcnt(8)" ::: "memory");   // T0 resident; T1 in flight
  __builtin_amdgcn_s_barrier();
  __builtin_amdgcn_sched_barrier(0);

  const int fr = lane & 15;
  const int g4 = lane >> 4;   // 0..3

#pragma unroll
  for (int kt = 0; kt < 4; ++kt) {
    const unsigned short* sA = smem + (kt & 1) * 32768;
    const unsigned short* sB = sA + 16384;
    bf16x8 af[4][2];            // current A quadrant, persists nh=0 -> nh=1
#pragma unroll
    for (int q = 0; q < 4; ++q) {
      const int mh = q >> 1, nh = q & 1;
      // --- ds-load register subtile ---
      if (nh == 0) {
#pragma unroll
        for (int m4 = 0; m4 < 4; ++m4)
#pragma unroll
          for (int k = 0; k < 2; ++k)
            af[m4][k] = ldsfrag(sA, wr * 128 + (mh * 4 + m4) * 16 + fr, k * 4 + g4);
      }
      bf16x8 bf[2][2];
#pragma unroll
      for (int n2 = 0; n2 < 2; ++n2)
#pragma unroll
        for (int k = 0; k < 2; ++k)
          bf[n2][k] = ldsfrag(sB, wc * 64 + (nh * 2 + n2) * 16 + fr, k * 4 + g4);
      // --- prefetch stage (to the slot NOT being read) ---
      if (kt == 1 && q == 0) stage_mat(gA, 2, smem,                 wid, lane);
      if (kt == 1 && q == 1) stage_mat(gB, 2, smem + 16384,         wid, lane);
      if (kt == 2 && q == 0) stage_mat(gA, 3, smem + 32768,         wid, lane);
      if (kt == 2 && q == 1) stage_mat(gB, 3, smem + 32768 + 16384, wid, lane);
      // --- phase sync + MFMA cluster ---
      __builtin_amdgcn_s_barrier();
      asm volatile("s_waitcnt lgkmcnt(0)" ::: "memory");
      __builtin_amdgcn_s_setprio(1);
#pragma unroll
      for (int m4 = 0; m4 < 4; ++m4)
#pragma unroll
        for (int n2 = 0; n2 < 2; ++n2)
#pragma unroll
          for (int k = 0; k < 2; ++k)
            acc[mh * 4 + m4][nh * 2 + n2] = __builtin_amdgcn_mfma_f32_16x16x32_bf16(
                af[m4][k], bf[n2][k], acc[mh * 4 + m4][nh * 2 + n2], 0, 0, 0);
      __builtin_amdgcn_s_setprio(0);
      if (q < 3) __builtin_amdgcn_s_barrier();
    }
    if (kt < 3) {
      // slot-swap boundary: next K-tile's loads must be resident
      asm volatile("s_waitcnt vmcnt(0)" ::: "memory");
      __builtin_amdgcn_s_barrier();
      __builtin_amdgcn_sched_barrier(0);
    }
  }

  // ---- epilogue: logits in [-1,1] -> plain exp; reduce 16 frag cols ----
  // C/D: col = lane&15 (within n*16), row = (lane>>4)*4 + reg (within m*16)
#pragma unroll
  for (int m = 0; m < 8; ++m)
#pragma unroll
    for (int r = 0; r < 4; ++r) {
      float s = 0.f;
#pragma unroll
      for (int n = 0; n < 4; ++n) s += __expf(acc[m][n][r]);
      s += __shfl_xor(s, 1);
      s += __shfl_xor(s, 2);
      s += __shfl_xor(s, 4);
      s += __shfl_xor(s, 8);
      if ((lane & 15) == 0) {
        int row   = bm * BM + wr * 128 + m * 16 + (lane >> 4) * 4 + r;
        int chunk = (bn << 2) | wc;
        partial[(size_t)row * NCHUNK + chunk] = s;
      }
    }
}

// ---------------- Kernel C: per-row finish: log(sum) - diag ----------------
__global__ void row_finish(const unsigned short* __restrict__ ohat,
                           const unsigned short* __restrict__ that,
                           const float* __restrict__ partial,
                           float* __restrict__ rowloss) {
  int row  = blockIdx.x * 4 + (threadIdx.x >> 6);
  int lane = threadIdx.x & 63;
  ushort4 ov = *(reinterpret_cast<const ushort4*>(ohat + (size_t)row * DIM) + lane);
  ushort4 tv = *(reinterpret_cast<const ushort4*>(that + (size_t)row * DIM) + lane);
  float d = b2f(ov.x) * b2f(tv.x) + b2f(ov.y) * b2f(tv.y) +
            b2f(ov.z) * b2f(tv.z) + b2f(ov.w) * b2f(tv.w);
  float4 p = *(reinterpret_cast<const float4*>(partial + (size_t)row * NCHUNK) + lane);
  float s = p.x + p.y + p.z + p.w;
#pragma unroll
  for (int m = 1; m < 64; m <<= 1) {
    d += __shfl_xor(d, m);
    s += __shfl_xor(s, m);
  }
  if (lane == 0) rowloss[row] = logf(s) - d;
}

// ---------------- Kernel D: mean over rows -> d_out[0] ----------------
__global__ void final_reduce(const float* __restrict__ rl, float* __restrict__ out) {
  __shared__ float sm[16];
  float s = 0.f;
  for (int i = threadIdx.x; i < BROWS; i += 1024) s += rl[i];
#pragma unroll
  for (int m = 1; m < 64; m <<= 1) s += __shfl_xor(s, m);
  int wid = threadIdx.x >> 6, lane = threadIdx.x & 63;
  if (lane == 0) sm[wid] = s;
  __syncthreads();
  if (wid == 0) {
    float v = (lane < 16) ? sm[lane] : 0.f;
#pragma unroll
    for (int m = 1; m < 16; m <<= 1) v += __shfl_xor(v, m);
    if (lane == 0) out[0] = v / (float)BROWS;
  }
}

extern "C" void kernel_launch(void* const* d_in, const int* in_sizes, int n_in,
                              void* d_out, int out_size, void* d_ws, size_t ws_size,
                              hipStream_t stream) {
  const float* outputs = (const float*)d_in[0];
  const float* targets = (const float*)d_in[1];
  float* out = (float*)d_out;
  char* ws = (char*)d_ws;

  unsigned short* ohat = (unsigned short*)ws;                                   // 8 MB
  unsigned short* that = (unsigned short*)(ws + (size_t)8 * 1024 * 1024);       // 8 MB
  float* partial       = (float*)(ws + (size_t)16 * 1024 * 1024);               // 16 MB
  float* rowloss       = (float*)(ws + (size_t)32 * 1024 * 1024);               // 64 KB

  normalize_rows<<<BROWS / 4, 256, 0, stream>>>(outputs, ohat);
  normalize_rows<<<BROWS / 4, 256, 0, stream>>>(targets, that);
  gemm_expsum<<<NBM * NBN, 512, 0, stream>>>(ohat, that, partial);
  row_finish<<<BROWS / 4, 256, 0, stream>>>(ohat, that, partial, rowloss);
  final_reduce<<<1, 1024, 0, stream>>>(rowloss, out);
}

// Round 4
// 218.649 us; speedup vs baseline: 1.0798x; 1.0798x over previous
//
#include <hip/hip_runtime.h>
#include <hip/hip_bf16.h>
#include <stdint.h>

#define BROWS 16384
#define DIM   256
#define BM    128
#define BN    128
#define BK    64
#define NBM   (BROWS / BM)      // 128 row blocks
#define NCHUNK 256              // 64-wide column chunks per row

#define LOG2E 1.44269504088896340736f
#define LN2   0.69314718055994530942f

typedef __attribute__((ext_vector_type(8))) short bf16x8;
typedef __attribute__((ext_vector_type(4))) float f32x4;

__device__ __forceinline__ float b2f(unsigned short u) {
  return __uint_as_float(((unsigned)u) << 16);
}
__device__ __forceinline__ unsigned short f2b(float f) {
  unsigned u = __float_as_uint(f);
  u += 0x7fffu + ((u >> 16) & 1u);   // RNE
  return (unsigned short)(u >> 16);
}
__device__ __forceinline__ float exp2_fast(float x) {
#if __has_builtin(__builtin_amdgcn_exp2f)
  return __builtin_amdgcn_exp2f(x);   // v_exp_f32 = 2^x
#else
  return exp2f(x);
#endif
}

__device__ __forceinline__ void gload_lds16(const void* g, void* l) {
  __builtin_amdgcn_global_load_lds(
      (const __attribute__((address_space(1))) void*)g,
      (__attribute__((address_space(3))) void*)l, 16, 0, 0);
}

// ---------------- Kernel A: row-normalize f32 -> bf16 (optional scale) ------
// ohat is additionally scaled by log2(e) so the GEMM epilogue can use 2^x.
__global__ void normalize_rows(const float* __restrict__ in,
                               unsigned short* __restrict__ out, float scale) {
  int row  = blockIdx.x * 4 + (threadIdx.x >> 6);
  int lane = threadIdx.x & 63;
  float4 v = *(reinterpret_cast<const float4*>(in + (size_t)row * DIM) + lane);
  float ss = v.x * v.x + v.y * v.y + v.z * v.z + v.w * v.w;
#pragma unroll
  for (int m = 1; m < 64; m <<= 1) ss += __shfl_xor(ss, m);
  float r = rsqrtf(ss) * scale;
  ushort4 o;
  o.x = f2b(v.x * r);
  o.y = f2b(v.y * r);
  o.z = f2b(v.z * r);
  o.w = f2b(v.w * r);
  *(reinterpret_cast<ushort4*>(out + (size_t)row * DIM) + lane) = o;
}

// Stage one 128x64 K-tile pair (A,B) into an LDS slot. LDS dest is linear
// (wave-uniform base + lane*16); the global SOURCE granule carries the bank
// swizzle: LDS granule h of row r holds global granule h^(r&7).
__device__ __forceinline__ void stage_tile(const unsigned short* gA,
                                           const unsigned short* gB, int kt,
                                           unsigned short* sA, unsigned short* sB,
                                           int wid, int srow, int sg) {
#pragma unroll
  for (int p = 0; p < 4; ++p) {
    int row  = p * 32 + srow;
    int goff = kt * BK + ((sg ^ (row & 7)) << 3);
    gload_lds16(gA + (size_t)row * DIM + goff, (char*)sA + p * 4096 + wid * 1024);
    gload_lds16(gB + (size_t)row * DIM + goff, (char*)sB + p * 4096 + wid * 1024);
  }
}

// ---------------- Kernel B: fused GEMM + exp2 + per-row partial sums --------
// 128x128 C-tile, 4 waves 2x2 (wave tile 64x64), 16x16x32 bf16 MFMA, BK=64,
// depth-1 double-buffered LDS (64 KiB): stage(kt+1) issued BEFORE compute(kt),
// single __syncthreads per K-step (its vmcnt(0) drain lands after ~460cy of
// cover). Epilogue: logits pre-scaled by log2e -> plain 2^x sum, no max.
__global__ __launch_bounds__(256, 4) void gemm_expsum(
    const unsigned short* __restrict__ A,   // ohat [BROWS][DIM] (scaled log2e)
    const unsigned short* __restrict__ Bm,  // that [BROWS][DIM]
    float* __restrict__ partial) {
  __shared__ unsigned short As[2][BM * BK];  // 2 x 16 KB
  __shared__ unsigned short Bs[2][BN * BK];  // 2 x 16 KB

  int tid  = threadIdx.x;
  int lane = tid & 63;
  int wid  = tid >> 6;
  int wr   = wid >> 1;      // wave row 0..1
  int wc   = wid & 1;       // wave col 0..1
  int bm   = blockIdx.x & (NBM - 1);
  int bn   = blockIdx.x >> 7;

  f32x4 acc[4][4];
#pragma unroll
  for (int m = 0; m < 4; ++m)
#pragma unroll
    for (int n = 0; n < 4; ++n) acc[m][n] = (f32x4){0.f, 0.f, 0.f, 0.f};

  const int srow = tid >> 3;   // 0..31: row within a 32-row staging pass
  const int sg   = tid & 7;    // 16B granule within the 64-elem row

  const unsigned short* gA = A  + (size_t)bm * BM * DIM;
  const unsigned short* gB = Bm + (size_t)bn * BN * DIM;

  // prologue: stage T0 -> slot0, drain
  stage_tile(gA, gB, 0, As[0], Bs[0], wid, srow, sg);
  __syncthreads();

  const int fr = lane & 15;
  const int g4 = lane >> 4;   // 0..3

#pragma unroll
  for (int kt = 0; kt < DIM / BK; ++kt) {   // 4 K-steps
    const unsigned short* sA = As[kt & 1];
    const unsigned short* sB = Bs[kt & 1];
    // issue next tile's loads into the other slot (safe: its readers finished
    // before the previous barrier), then compute current under their latency
    if (kt < 3)
      stage_tile(gA, gB, kt + 1, As[(kt + 1) & 1], Bs[(kt + 1) & 1], wid, srow, sg);
    __builtin_amdgcn_sched_barrier(0);   // keep load-issue ahead of ds_reads

#pragma unroll
    for (int kk = 0; kk < 2; ++kk) {
      int gk  = kk * 4 + g4;             // wanted 16B granule (0..7)
      bf16x8 af[4], bfr[4];
#pragma unroll
      for (int m = 0; m < 4; ++m) {
        int row = wr * 64 + m * 16 + fr;
        af[m] = *reinterpret_cast<const bf16x8*>(&sA[row * BK + ((gk ^ (row & 7)) << 3)]);
      }
#pragma unroll
      for (int n = 0; n < 4; ++n) {
        int row = wc * 64 + n * 16 + fr;
        bfr[n] = *reinterpret_cast<const bf16x8*>(&sB[row * BK + ((gk ^ (row & 7)) << 3)]);
      }
#pragma unroll
      for (int m = 0; m < 4; ++m)
#pragma unroll
        for (int n = 0; n < 4; ++n)
          acc[m][n] = __builtin_amdgcn_mfma_f32_16x16x32_bf16(af[m], bfr[n], acc[m][n], 0, 0, 0);
    }
    if (kt < 3) __syncthreads();   // drains vmcnt(0): next slot resident
  }

  // ---- epilogue: S = log2e * logit, bounded -> sum of 2^S ----
  // C/D layout: col = lane&15, row = (lane>>4)*4 + reg
  float esum[4][4];
#pragma unroll
  for (int m = 0; m < 4; ++m)
#pragma unroll
    for (int r = 0; r < 4; ++r) {
      float s = 0.f;
#pragma unroll
      for (int n = 0; n < 4; ++n) s += exp2_fast(acc[m][n][r]);
      esum[m][r] = s;
    }
#pragma unroll
  for (int m = 0; m < 4; ++m)
#pragma unroll
    for (int r = 0; r < 4; ++r) {
      float s = esum[m][r];
      s += __shfl_xor(s, 1);
      s += __shfl_xor(s, 2);
      s += __shfl_xor(s, 4);
      s += __shfl_xor(s, 8);
      esum[m][r] = s;
    }
  if ((lane & 15) == 0) {
    int sub   = lane >> 4;              // 0..3
    int chunk = (bn << 1) | wc;         // 0..255
    int rbase = bm * BM + wr * 64;
#pragma unroll
    for (int m = 0; m < 4; ++m)
#pragma unroll
      for (int r = 0; r < 4; ++r)
        partial[(size_t)(rbase + m * 16 + sub * 4 + r) * NCHUNK + chunk] = esum[m][r];
  }
}

// ---------------- Kernel C: per-row finish: log(sum) - diag ----------------
// d (from scaled ohat) = log2e * true diag logit -> multiply by ln2.
__global__ void row_finish(const unsigned short* __restrict__ ohat,
                           const unsigned short* __restrict__ that,
                           const float* __restrict__ partial,
                           float* __restrict__ rowloss) {
  int row  = blockIdx.x * 4 + (threadIdx.x >> 6);
  int lane = threadIdx.x & 63;
  ushort4 ov = *(reinterpret_cast<const ushort4*>(ohat + (size_t)row * DIM) + lane);
  ushort4 tv = *(reinterpret_cast<const ushort4*>(that + (size_t)row * DIM) + lane);
  float d = b2f(ov.x) * b2f(tv.x) + b2f(ov.y) * b2f(tv.y) +
            b2f(ov.z) * b2f(tv.z) + b2f(ov.w) * b2f(tv.w);
  float4 p = *(reinterpret_cast<const float4*>(partial + (size_t)row * NCHUNK) + lane);
  float s = p.x + p.y + p.z + p.w;
#pragma unroll
  for (int m = 1; m < 64; m <<= 1) {
    d += __shfl_xor(d, m);
    s += __shfl_xor(s, m);
  }
  if (lane == 0) rowloss[row] = logf(s) - d * LN2;
}

// ---------------- Kernel D: mean over rows -> d_out[0] ----------------
__global__ void final_reduce(const float* __restrict__ rl, float* __restrict__ out) {
  __shared__ float sm[16];
  float s = 0.f;
  for (int i = threadIdx.x; i < BROWS; i += 1024) s += rl[i];
#pragma unroll
  for (int m = 1; m < 64; m <<= 1) s += __shfl_xor(s, m);
  int wid = threadIdx.x >> 6, lane = threadIdx.x & 63;
  if (lane == 0) sm[wid] = s;
  __syncthreads();
  if (wid == 0) {
    float v = (lane < 16) ? sm[lane] : 0.f;
#pragma unroll
    for (int m = 1; m < 16; m <<= 1) v += __shfl_xor(v, m);
    if (lane == 0) out[0] = v / (float)BROWS;
  }
}

extern "C" void kernel_launch(void* const* d_in, const int* in_sizes, int n_in,
                              void* d_out, int out_size, void* d_ws, size_t ws_size,
                              hipStream_t stream) {
  const float* outputs = (const float*)d_in[0];
  const float* targets = (const float*)d_in[1];
  float* out = (float*)d_out;
  char* ws = (char*)d_ws;

  unsigned short* ohat = (unsigned short*)ws;                                   // 8 MB
  unsigned short* that = (unsigned short*)(ws + (size_t)8 * 1024 * 1024);       // 8 MB
  float* partial       = (float*)(ws + (size_t)16 * 1024 * 1024);               // 16 MB
  float* rowloss       = (float*)(ws + (size_t)32 * 1024 * 1024);               // 64 KB

  normalize_rows<<<BROWS / 4, 256, 0, stream>>>(outputs, ohat, LOG2E);
  normalize_rows<<<BROWS / 4, 256, 0, stream>>>(targets, that, 1.0f);
  gemm_expsum<<<NBM * (BROWS / BN), 256, 0, stream>>>(ohat, that, partial);
  row_finish<<<BROWS / 4, 256, 0, stream>>>(ohat, that, partial, rowloss);
  final_reduce<<<1, 1024, 0, stream>>>(rowloss, out);
}

// Round 5
// 143.097 us; speedup vs baseline: 1.6500x; 1.5280x over previous
//
#include <hip/hip_runtime.h>
#include <hip/hip_bf16.h>
#include <stdint.h>

#define BROWS 16384
#define DIM   256
#define BM    128
#define BN    128
#define BKB   128               // K-tile in BYTES (fp8: 128 elems)
#define NBM   (BROWS / BM)      // 128 row blocks
#define NCHUNK 256              // 64-wide column chunks per row

#define LOG2E 1.44269504088896340736f

typedef __attribute__((ext_vector_type(8))) int  i32x8;
typedef __attribute__((ext_vector_type(4))) float f32x4;
typedef unsigned char uchar;

__device__ __forceinline__ float exp2_fast(float x) { return exp2f(x); }

__device__ __forceinline__ void gload_lds16(const void* g, void* l) {
  __builtin_amdgcn_global_load_lds(
      (const __attribute__((address_space(1))) void*)g,
      (__attribute__((address_space(3))) void*)l, 16, 0, 0);
}

// ---------------- Kernel A: row-normalize f32 -> fp8 e4m3 + inv-norm --------
// out8 row r = fp8(x * rsqrt(ss) * scale); invn[r] = rsqrt(ss) (exact f32).
__global__ void normalize_fp8(const float* __restrict__ in,
                              uchar* __restrict__ out8,
                              float* __restrict__ invn, float scale) {
  int row  = blockIdx.x * 4 + (threadIdx.x >> 6);
  int lane = threadIdx.x & 63;
  float4 v = *(reinterpret_cast<const float4*>(in + (size_t)row * DIM) + lane);
  float ss = v.x * v.x + v.y * v.y + v.z * v.z + v.w * v.w;
#pragma unroll
  for (int m = 1; m < 64; m <<= 1) ss += __shfl_xor(ss, m);
  float r = rsqrtf(ss);
  if (lane == 0) invn[row] = r;
  float q = r * scale;
  int w = 0;
  w = __builtin_amdgcn_cvt_pk_fp8_f32(v.x * q, v.y * q, w, false);
  w = __builtin_amdgcn_cvt_pk_fp8_f32(v.z * q, v.w * q, w, true);
  reinterpret_cast<int*>(out8 + (size_t)row * DIM)[lane] = w;
}

// Stage one 128-row x 128-byte K-tile pair (A,B) into LDS. LDS dest is linear
// (wave-uniform base + lane*16); the global SOURCE granule carries the bank
// swizzle: LDS granule h of row r holds global granule h^(r&7).
__device__ __forceinline__ void stage_tile8(const uchar* gA, const uchar* gB,
                                            int kt, uchar* sA, uchar* sB,
                                            int wid, int srow, int sg) {
#pragma unroll
  for (int p = 0; p < 4; ++p) {
    int row  = p * 32 + srow;
    int goff = kt * BKB + ((sg ^ (row & 7)) << 4);   // byte offset in row
    gload_lds16(gA + (size_t)row * DIM + goff, sA + p * 4096 + wid * 1024);
    gload_lds16(gB + (size_t)row * DIM + goff, sB + p * 4096 + wid * 1024);
  }
}

// ---------------- Kernel B: fp8 GEMM (MX scale=1) + exp2 + partial sums -----
// 128x128 C-tile, 4 waves 2x2 (wave tile 64x64), mfma_scale 16x16x128 fp8,
// identity E8M0 scales (0x7F = 2^0). K=256 = 2 K-tiles, single-buffer 32 KiB.
// A/B frag: lane l holds row (l&15), k-bytes [(l>>4)*32, +32) (2 b128 reads).
// C/D layout (shape-determined, same as 16x16x32): col=lane&15, row=(l>>4)*4+reg.
__global__ __launch_bounds__(256, 4) void gemm_expsum(
    const uchar* __restrict__ A8,   // ohat fp8 [BROWS][DIM], pre-scaled log2e
    const uchar* __restrict__ B8,   // that fp8 [BROWS][DIM] (rows = logits cols)
    float* __restrict__ partial) {
  __shared__ __align__(16) uchar As[BM * BKB];  // 16 KB
  __shared__ __align__(16) uchar Bs[BN * BKB];  // 16 KB

  int tid  = threadIdx.x;
  int lane = tid & 63;
  int wid  = tid >> 6;
  int wr   = wid >> 1;      // wave row 0..1
  int wc   = wid & 1;       // wave col 0..1
  int bm   = blockIdx.x & (NBM - 1);
  int bn   = blockIdx.x >> 7;

  f32x4 acc[4][4];
#pragma unroll
  for (int m = 0; m < 4; ++m)
#pragma unroll
    for (int n = 0; n < 4; ++n) acc[m][n] = (f32x4){0.f, 0.f, 0.f, 0.f};

  const int srow = tid >> 3;   // 0..31: row within a 32-row staging pass
  const int sg   = tid & 7;    // 16B granule within the 128B row-chunk

  const uchar* gA = A8 + (size_t)bm * BM * DIM;
  const uchar* gB = B8 + (size_t)bn * BN * DIM;

  const int fr = lane & 15;
  const int kc = lane >> 4;    // 0..3: which 32-byte K-chunk this lane owns

#pragma unroll
  for (int kt = 0; kt < 2; ++kt) {
    stage_tile8(gA, gB, kt, As, Bs, wid, srow, sg);
    __syncthreads();   // drains vmcnt(0): tile resident

    i32x8 af[4];
#pragma unroll
    for (int m = 0; m < 4; ++m) {
      int row = wr * 64 + m * 16 + fr;
      int ra  = row * BKB;
      const int4 lo = *reinterpret_cast<const int4*>(As + ra + ((((kc << 1)    ) ^ (row & 7)) << 4));
      const int4 hi = *reinterpret_cast<const int4*>(As + ra + ((((kc << 1) | 1) ^ (row & 7)) << 4));
      af[m] = (i32x8){lo.x, lo.y, lo.z, lo.w, hi.x, hi.y, hi.z, hi.w};
    }
#pragma unroll
    for (int n = 0; n < 4; ++n) {
      int row = wc * 64 + n * 16 + fr;
      int rb  = row * BKB;
      const int4 lo = *reinterpret_cast<const int4*>(Bs + rb + ((((kc << 1)    ) ^ (row & 7)) << 4));
      const int4 hi = *reinterpret_cast<const int4*>(Bs + rb + ((((kc << 1) | 1) ^ (row & 7)) << 4));
      i32x8 bf = (i32x8){lo.x, lo.y, lo.z, lo.w, hi.x, hi.y, hi.z, hi.w};
#pragma unroll
      for (int m = 0; m < 4; ++m)
        acc[m][n] = __builtin_amdgcn_mfma_scale_f32_16x16x128_f8f6f4(
            af[m], bf, acc[m][n], 0, 0,                 // cbsz=fp8, blgp=fp8
            0, 0x7F7F7F7F, 0, 0x7F7F7F7F);              // identity E8M0 scales
    }
    if (kt == 0) __syncthreads();   // readers done before next stage overwrites
  }

  // ---- epilogue: S = log2e * logit (bounded) -> v[j] = sum_n 2^S ----
  // C/D: col = lane&15, row = (lane>>4)*4 + reg (within each 16x16 frag)
  float v[16];
#pragma unroll
  for (int j = 0; j < 16; ++j) {
    int m = j >> 2, r = j & 3;
    v[j] = exp2_fast(acc[m][0][r]) + exp2_fast(acc[m][1][r]) +
           exp2_fast(acc[m][2][r]) + exp2_fast(acc[m][3][r]);
  }
  // butterfly-bisect reduce over the 16 fragment columns: 8+4+2+1 = 15 shfl;
  // afterwards lane holds the full sum of original v[lane&15].
#pragma unroll
  for (int s = 0; s < 4; ++s) {
    const int len = 16 >> s;
    const int bit = (lane >> s) & 1;
#pragma unroll
    for (int t = 0; t < 8; ++t) {
      if (t < (len >> 1)) {
        float a = v[2 * t], b = v[2 * t + 1];
        float recv = __shfl_xor(bit ? a : b, 1 << s);
        v[t] = (bit ? b : a) + recv;
      }
    }
  }
  {
    int j     = lane & 15;
    int sub   = lane >> 4;
    int row   = bm * BM + wr * 64 + (j >> 2) * 16 + sub * 4 + (j & 3);
    int chunk = (bn << 1) | wc;
    partial[(size_t)row * NCHUNK + chunk] = v[0];
  }
}

// ---------------- Kernel C: per-row finish: log(sum) - exact diag ----------
__global__ void row_finish(const float* __restrict__ o,
                           const float* __restrict__ t,
                           const float* __restrict__ invo,
                           const float* __restrict__ invt,
                           const float* __restrict__ partial,
                           float* __restrict__ rowloss) {
  int row  = blockIdx.x * 4 + (threadIdx.x >> 6);
  int lane = threadIdx.x & 63;
  float4 a = *(reinterpret_cast<const float4*>(o + (size_t)row * DIM) + lane);
  float4 b = *(reinterpret_cast<const float4*>(t + (size_t)row * DIM) + lane);
  float d  = a.x * b.x + a.y * b.y + a.z * b.z + a.w * b.w;
  float4 p = *(reinterpret_cast<const float4*>(partial + (size_t)row * NCHUNK) + lane);
  float s  = p.x + p.y + p.z + p.w;
#pragma unroll
  for (int m = 1; m < 64; m <<= 1) {
    d += __shfl_xor(d, m);
    s += __shfl_xor(s, m);
  }
  if (lane == 0) rowloss[row] = logf(s) - d * invo[row] * invt[row];
}

// ---------------- Kernel D: mean over rows -> d_out[0] ----------------
__global__ void final_reduce(const float* __restrict__ rl, float* __restrict__ out) {
  __shared__ float sm[16];
  float s = 0.f;
  for (int i = threadIdx.x; i < BROWS; i += 1024) s += rl[i];
#pragma unroll
  for (int m = 1; m < 64; m <<= 1) s += __shfl_xor(s, m);
  int wid = threadIdx.x >> 6, lane = threadIdx.x & 63;
  if (lane == 0) sm[wid] = s;
  __syncthreads();
  if (wid == 0) {
    float v = (lane < 16) ? sm[lane] : 0.f;
#pragma unroll
    for (int m = 1; m < 16; m <<= 1) v += __shfl_xor(v, m);
    if (lane == 0) out[0] = v / (float)BROWS;
  }
}

extern "C" void kernel_launch(void* const* d_in, const int* in_sizes, int n_in,
                              void* d_out, int out_size, void* d_ws, size_t ws_size,
                              hipStream_t stream) {
  const float* outputs = (const float*)d_in[0];
  const float* targets = (const float*)d_in[1];
  float* out = (float*)d_out;
  char* ws = (char*)d_ws;

  uchar* o8      = (uchar*)ws;                                      // 4 MB
  uchar* t8      = (uchar*)(ws + (size_t)4 * 1024 * 1024);          // 4 MB
  float* partial = (float*)(ws + (size_t)8 * 1024 * 1024);          // 16 MB
  float* invo    = (float*)(ws + (size_t)24 * 1024 * 1024);         // 64 KB
  float* invt    = (float*)(ws + (size_t)24 * 1024 * 1024 + 65536); // 64 KB
  float* rowloss = (float*)(ws + (size_t)24 * 1024 * 1024 + 131072);// 64 KB

  normalize_fp8<<<BROWS / 4, 256, 0, stream>>>(outputs, o8, invo, LOG2E);
  normalize_fp8<<<BROWS / 4, 256, 0, stream>>>(targets, t8, invt, 1.0f);
  gemm_expsum<<<NBM * (BROWS / BN), 256, 0, stream>>>(o8, t8, partial);
  row_finish<<<BROWS / 4, 256, 0, stream>>>(outputs, targets, invo, invt, partial, rowloss);
  final_reduce<<<1, 1024, 0, stream>>>(rowloss, out);
}

// Round 6
// 128.947 us; speedup vs baseline: 1.8310x; 1.1097x over previous
//
#include <hip/hip_runtime.h>
#include <hip/hip_bf16.h>
#include <stdint.h>

#define BROWS 16384
#define DIM   256
#define BM    128
#define BN    128
#define BKB   128               // K-tile in BYTES (fp8: 128 elems)
#define NBM   (BROWS / BM)      // 128 row blocks
#define NCHUNK 256              // 64-wide column chunks per row

#define LOG2E 1.44269504088896340736f

typedef __attribute__((ext_vector_type(8))) int  i32x8;
typedef __attribute__((ext_vector_type(4))) float f32x4;
typedef unsigned char uchar;

__device__ __forceinline__ void gload_lds16(const void* g, void* l) {
  __builtin_amdgcn_global_load_lds(
      (const __attribute__((address_space(1))) void*)g,
      (__attribute__((address_space(3))) void*)l, 16, 0, 0);
}

// ---------------- Kernel A1: row-normalize f32 -> fp8 e4m3 + inv-norm -------
__global__ void normalize_fp8(const float* __restrict__ in,
                              uchar* __restrict__ out8,
                              float* __restrict__ invn, float scale) {
  int row  = blockIdx.x * 4 + (threadIdx.x >> 6);
  int lane = threadIdx.x & 63;
  float4 v = *(reinterpret_cast<const float4*>(in + (size_t)row * DIM) + lane);
  float ss = v.x * v.x + v.y * v.y + v.z * v.z + v.w * v.w;
#pragma unroll
  for (int m = 1; m < 64; m <<= 1) ss += __shfl_xor(ss, m);
  float r = rsqrtf(ss);
  if (lane == 0) invn[row] = r;
  float q = r * scale;
  int w = 0;
  w = __builtin_amdgcn_cvt_pk_fp8_f32(v.x * q, v.y * q, w, false);
  w = __builtin_amdgcn_cvt_pk_fp8_f32(v.z * q, v.w * q, w, true);
  reinterpret_cast<int*>(out8 + (size_t)row * DIM)[lane] = w;
}

// ---------------- Kernel A2: normalize targets + exact diag -----------------
// Also computes dlog[row] = <o_row, t_row> * invo[row] * invt[row] (exact f32)
__global__ void normalize_fp8_diag(const float* __restrict__ t,
                                   const float* __restrict__ o,
                                   uchar* __restrict__ out8,
                                   const float* __restrict__ invo,
                                   float* __restrict__ dlog) {
  int row  = blockIdx.x * 4 + (threadIdx.x >> 6);
  int lane = threadIdx.x & 63;
  float4 v = *(reinterpret_cast<const float4*>(t + (size_t)row * DIM) + lane);
  float4 a = *(reinterpret_cast<const float4*>(o + (size_t)row * DIM) + lane);
  float ss = v.x * v.x + v.y * v.y + v.z * v.z + v.w * v.w;
  float d  = a.x * v.x + a.y * v.y + a.z * v.z + a.w * v.w;
#pragma unroll
  for (int m = 1; m < 64; m <<= 1) {
    ss += __shfl_xor(ss, m);
    d  += __shfl_xor(d, m);
  }
  float r = rsqrtf(ss);
  if (lane == 0) dlog[row] = d * invo[row] * r;
  int w = 0;
  w = __builtin_amdgcn_cvt_pk_fp8_f32(v.x * r, v.y * r, w, false);
  w = __builtin_amdgcn_cvt_pk_fp8_f32(v.z * r, v.w * r, w, true);
  reinterpret_cast<int*>(out8 + (size_t)row * DIM)[lane] = w;
}

// Stage one 128-row x 128-byte K-tile pair (A,B) into LDS. LDS dest is linear
// (wave-uniform base + lane*16); the global SOURCE carries the bank swizzle at
// 32B granularity: LDS granule32 h of row r holds global granule32 h^(r&3).
__device__ __forceinline__ void stage_tile8(const uchar* gA, const uchar* gB,
                                            int kt, uchar* sA, uchar* sB,
                                            int wid, int srow, int sg) {
#pragma unroll
  for (int p = 0; p < 4; ++p) {
    int row  = p * 32 + srow;
    int g16  = ((((sg >> 1) ^ (row & 3)) << 1) | (sg & 1));  // src 16B granule
    int goff = kt * BKB + (g16 << 4);
    gload_lds16(gA + (size_t)row * DIM + goff, sA + p * 4096 + wid * 1024);
    gload_lds16(gB + (size_t)row * DIM + goff, sB + p * 4096 + wid * 1024);
  }
}

// ---------------- Kernel B: fp8 GEMM (MX scale=1) + exp2 + partial sums -----
// 128x128 C-tile, 4 waves 2x2 (wave tile 64x64), mfma_scale 16x16x128 fp8,
// identity E8M0 scales. K=256 = 2 K-tiles, single-buffer 32 KiB.
// A/B frag: lane l holds row (l&15), K-bytes [(l>>4)*32, +32) as ONE aligned
// i32x8 (2x ds_read_b128). C/D: col=lane&15, row=(l>>4)*4+reg.
__global__ __launch_bounds__(256, 3) void gemm_expsum(
    const uchar* __restrict__ A8,   // ohat fp8, pre-scaled by log2e
    const uchar* __restrict__ B8,   // that fp8 (rows = logits cols)
    float* __restrict__ partial) {
  __shared__ __align__(32) uchar As[BM * BKB];  // 16 KB
  __shared__ __align__(32) uchar Bs[BN * BKB];  // 16 KB

  int tid  = threadIdx.x;
  int lane = tid & 63;
  int wid  = tid >> 6;
  int wr   = wid >> 1;      // wave row 0..1
  int wc   = wid & 1;       // wave col 0..1
  int bm   = blockIdx.x & (NBM - 1);
  int bn   = blockIdx.x >> 7;

  f32x4 acc[4][4];
#pragma unroll
  for (int m = 0; m < 4; ++m)
#pragma unroll
    for (int n = 0; n < 4; ++n) acc[m][n] = (f32x4){0.f, 0.f, 0.f, 0.f};

  const int srow = tid >> 3;   // 0..31: row within a 32-row staging pass
  const int sg   = tid & 7;    // 16B granule within the 128B row-chunk

  const uchar* gA = A8 + (size_t)bm * BM * DIM;
  const uchar* gB = B8 + (size_t)bn * BN * DIM;

  const int fr = lane & 15;
  const int kc = lane >> 4;    // 0..3: which 32-byte K-chunk this lane owns

#pragma unroll
  for (int kt = 0; kt < 2; ++kt) {
    stage_tile8(gA, gB, kt, As, Bs, wid, srow, sg);
    __syncthreads();   // drains vmcnt(0): tile resident

    i32x8 bf[4];
#pragma unroll
    for (int n = 0; n < 4; ++n) {
      int row = wc * 64 + n * 16 + fr;
      bf[n] = *reinterpret_cast<const i32x8*>(Bs + row * BKB + ((kc ^ (row & 3)) << 5));
    }
#pragma unroll
    for (int m = 0; m < 4; ++m) {
      int row = wr * 64 + m * 16 + fr;
      i32x8 af = *reinterpret_cast<const i32x8*>(As + row * BKB + ((kc ^ (row & 3)) << 5));
#pragma unroll
      for (int n = 0; n < 4; ++n)
        acc[m][n] = __builtin_amdgcn_mfma_scale_f32_16x16x128_f8f6f4(
            af, bf[n], acc[m][n], 0, 0,               // cbsz=fp8, blgp=fp8
            0, 0x7F7F7F7F, 0, 0x7F7F7F7F);            // identity E8M0 scales
    }
    if (kt == 0) __syncthreads();   // readers done before next stage overwrites
  }

  // ---- epilogue: S = log2e * logit (bounded) -> v[j] = sum_n 2^S ----
  float v[16];
#pragma unroll
  for (int j = 0; j < 16; ++j) {
    int m = j >> 2, r = j & 3;
    v[j] = exp2f(acc[m][0][r]) + exp2f(acc[m][1][r]) +
           exp2f(acc[m][2][r]) + exp2f(acc[m][3][r]);
  }
  // butterfly-bisect over the 16 fragment columns: 15 shfl; lane ends with the
  // full column-sum for row-index j = lane&15.
#pragma unroll
  for (int s = 0; s < 4; ++s) {
    const int len = 16 >> s;
    const int bit = (lane >> s) & 1;
#pragma unroll
    for (int t = 0; t < 8; ++t) {
      if (t < (len >> 1)) {
        float a = v[2 * t], b = v[2 * t + 1];
        float recv = __shfl_xor(bit ? a : b, 1 << s);
        v[t] = (bit ? b : a) + recv;
      }
    }
  }
  {
    int j     = lane & 15;
    int sub   = lane >> 4;
    int row   = bm * BM + wr * 64 + (j >> 2) * 16 + sub * 4 + (j & 3);
    int chunk = (bn << 1) | wc;
    partial[(size_t)row * NCHUNK + chunk] = v[0];
  }
}

// ---------------- Kernel C: per-row finish: log(sum) - exact diag ----------
__global__ void row_finish(const float* __restrict__ partial,
                           const float* __restrict__ dlog,
                           float* __restrict__ rowloss) {
  int row  = blockIdx.x * 4 + (threadIdx.x >> 6);
  int lane = threadIdx.x & 63;
  float4 p = *(reinterpret_cast<const float4*>(partial + (size_t)row * NCHUNK) + lane);
  float s  = p.x + p.y + p.z + p.w;
#pragma unroll
  for (int m = 1; m < 64; m <<= 1) s += __shfl_xor(s, m);
  if (lane == 0) rowloss[row] = logf(s) - dlog[row];
}

// ---------------- Kernel D: mean over rows -> d_out[0] ----------------
__global__ void final_reduce(const float* __restrict__ rl, float* __restrict__ out) {
  __shared__ float sm[16];
  float s = 0.f;
  for (int i = threadIdx.x; i < BROWS; i += 1024) s += rl[i];
#pragma unroll
  for (int m = 1; m < 64; m <<= 1) s += __shfl_xor(s, m);
  int wid = threadIdx.x >> 6, lane = threadIdx.x & 63;
  if (lane == 0) sm[wid] = s;
  __syncthreads();
  if (wid == 0) {
    float v = (lane < 16) ? sm[lane] : 0.f;
#pragma unroll
    for (int m = 1; m < 16; m <<= 1) v += __shfl_xor(v, m);
    if (lane == 0) out[0] = v / (float)BROWS;
  }
}

extern "C" void kernel_launch(void* const* d_in, const int* in_sizes, int n_in,
                              void* d_out, int out_size, void* d_ws, size_t ws_size,
                              hipStream_t stream) {
  const float* outputs = (const float*)d_in[0];
  const float* targets = (const float*)d_in[1];
  float* out = (float*)d_out;
  char* ws = (char*)d_ws;

  uchar* o8      = (uchar*)ws;                                      // 4 MB
  uchar* t8      = (uchar*)(ws + (size_t)4 * 1024 * 1024);          // 4 MB
  float* partial = (float*)(ws + (size_t)8 * 1024 * 1024);          // 16 MB
  float* invo    = (float*)(ws + (size_t)24 * 1024 * 1024);         // 64 KB
  float* dlog    = (float*)(ws + (size_t)24 * 1024 * 1024 + 65536); // 64 KB
  float* rowloss = (float*)(ws + (size_t)24 * 1024 * 1024 + 131072);// 64 KB

  normalize_fp8<<<BROWS / 4, 256, 0, stream>>>(outputs, o8, invo, LOG2E);
  normalize_fp8_diag<<<BROWS / 4, 256, 0, stream>>>(targets, outputs, t8, invo, dlog);
  gemm_expsum<<<NBM * (BROWS / BN), 256, 0, stream>>>(o8, t8, partial);
  row_finish<<<BROWS / 4, 256, 0, stream>>>(partial, dlog, rowloss);
  final_reduce<<<1, 1024, 0, stream>>>(rowloss, out);
}